// Round 2
// baseline (61316.473 us; speedup 1.0000x reference)
//
#include <hip/hip_runtime.h>
#include <cmath>

#define B_ 256
#define V_ 2048
#define T_ 196
#define Q_ 1024
#define M_ 512
#define NL 3
#define BT_ (B_*T_)

__device__ __forceinline__ float sigmf_(float x){ return 1.0f/(1.0f+expf(-x)); }

// ---------------- conv: vseq[t][b][m] = relu(sum_v vis[b][v][t]*cw[m][v])
// rows r=b*T_+t (128/tile), cols m (64/tile), K=V_ (32/tile). vis is [k][t]-contig.
__global__ __launch_bounds__(256) void k_conv(const float* __restrict__ vis,
        const float* __restrict__ cw, float* __restrict__ vseq){
  const int r0 = blockIdx.x*128, m0 = blockIdx.y*64;
  const int tid = threadIdx.x, tx = tid&15, ty = tid>>4;
  __shared__ float As[32][129];   // [k][row]
  __shared__ float Ws[64][33];    // [m][k]
  float acc[8][4] = {};
  const int rl = tid & 127;
  const int row_l = r0 + rl;
  const int bl = row_l / T_;
  const int tl = row_l - bl*T_;
  const int kh = tid >> 7;  // 0..1
  for (int kt=0; kt<64; ++kt){
    const int v0 = kt*32;
    __syncthreads();
    #pragma unroll
    for (int rr=0; rr<16; ++rr){
      int kl = kh + rr*2;
      As[kl][rl] = vis[((size_t)bl*V_ + v0 + kl)*T_ + tl];
    }
    {
      int ml = tid>>5, kl = tid&31;
      #pragma unroll
      for (int rr=0; rr<8; ++rr)
        Ws[ml+rr*8][kl] = cw[(size_t)(m0+ml+rr*8)*V_ + v0 + kl];
    }
    __syncthreads();
    #pragma unroll
    for (int kk=0; kk<32; ++kk){
      float w_[4];
      #pragma unroll
      for (int j=0;j<4;++j) w_[j] = Ws[tx*4+j][kk];
      #pragma unroll
      for (int i=0;i<8;++i){
        float a = As[kk][ty*8+i];
        #pragma unroll
        for (int j=0;j<4;++j) acc[i][j] += a*w_[j];
      }
    }
  }
  #pragma unroll
  for (int i=0;i<8;++i){
    int row = r0 + ty*8 + i;
    int b = row / T_;
    int t = row - b*T_;
    float* dst = vseq + ((size_t)t*B_ + b)*M_ + m0 + tx*4;
    float4 o;
    o.x = fmaxf(acc[i][0],0.f); o.y = fmaxf(acc[i][1],0.f);
    o.z = fmaxf(acc[i][2],0.f); o.w = fmaxf(acc[i][3],0.f);
    *(float4*)dst = o;
  }
}

// ---------------- linq: q[b][m] = relu(qf[b]·lw[m] + lb[m]), K=Q_
__global__ __launch_bounds__(256) void k_linq(const float* __restrict__ A,
    const float* __restrict__ W, const float* __restrict__ bias,
    float* __restrict__ out){
  const int r0 = blockIdx.x*64, m0 = blockIdx.y*64;
  const int tid = threadIdx.x, tx = tid&15, ty = tid>>4;
  __shared__ float As[64][33], Ws[64][33];
  float acc[4][4] = {};
  for (int kt=0; kt<32; ++kt){
    const int k0 = kt*32;
    __syncthreads();
    {
      int rl = tid>>5, kl = tid&31;
      #pragma unroll
      for (int rr=0; rr<8; ++rr){
        As[rl+rr*8][kl] = A[(size_t)(r0+rl+rr*8)*Q_ + k0+kl];
        Ws[rl+rr*8][kl] = W[(size_t)(m0+rl+rr*8)*Q_ + k0+kl];
      }
    }
    __syncthreads();
    #pragma unroll
    for (int kk=0;kk<32;++kk){
      float w_[4], a_[4];
      #pragma unroll
      for (int j=0;j<4;++j) w_[j] = Ws[tx*4+j][kk];
      #pragma unroll
      for (int i=0;i<4;++i) a_[i] = As[ty*4+i][kk];
      #pragma unroll
      for (int i=0;i<4;++i)
        #pragma unroll
        for (int j=0;j<4;++j) acc[i][j] += a_[i]*w_[j];
    }
  }
  #pragma unroll
  for (int i=0;i<4;++i)
    #pragma unroll
    for (int j=0;j<4;++j)
      out[(size_t)(r0+ty*4+i)*M_ + m0+tx*4+j] = fmaxf(acc[i][j] + bias[m0+tx*4+j], 0.f);
}

// ---------------- GRU step (both directions), input-proj fused. K=512(h)+512(x)
__global__ __launch_bounds__(256) void k_gru(
    const float* __restrict__ vseq,
    const float* __restrict__ hf_in, float* __restrict__ hf_out,
    const float* __restrict__ hb_in, float* __restrict__ hb_out,
    const float* __restrict__ wif, const float* __restrict__ whf,
    const float* __restrict__ bif, const float* __restrict__ bhf,
    const float* __restrict__ wib, const float* __restrict__ whb,
    const float* __restrict__ bib, const float* __restrict__ bhb,
    float* __restrict__ facts, float* __restrict__ bwds, int s){
  const int dir = blockIdx.z;
  const int b0 = blockIdx.x*64, j0 = blockIdx.y*16;
  const int tid = threadIdx.x, tb = tid&15, tj = tid>>4;
  const int te = dir ? (T_-1-s) : s;
  const float* hin = dir? hb_in : hf_in;
  float* hout = dir? hb_out : hf_out;
  const float* wi = dir? wib : wif;
  const float* wh = dir? whb : whf;
  const float* bi = dir? bib : bif;
  const float* bh = dir? bhb : bhf;
  const float* xb = vseq + (size_t)te*B_*M_;
  float* seqd = dir? bwds : facts;

  __shared__ float As[64][33];
  __shared__ float Ws[48][33];
  float accR[4]={0,0,0,0}, accZ[4]={0,0,0,0}, accH[4]={0,0,0,0}, accX[4]={0,0,0,0};

  // phase 0: h-side (weights wh), accumulate n-part into accH
  for (int kt=0; kt<16; ++kt){
    const int kb = kt*32;
    __syncthreads();
    {
      int rl = tid>>5, kl = tid&31;
      #pragma unroll
      for (int rr=0; rr<8; ++rr)
        As[rl+rr*8][kl] = hin[(size_t)(b0+rl+rr*8)*M_ + kb + kl];
      #pragma unroll
      for (int rr=0; rr<6; ++rr){
        int w = rl + rr*8;
        int gi = w>>4, jl = w&15;
        Ws[w][kl] = wh[(size_t)(gi*M_ + j0 + jl)*M_ + kb + kl];
      }
    }
    __syncthreads();
    #pragma unroll
    for (int kk=0; kk<32; ++kk){
      float wr = Ws[tj][kk], wz = Ws[16+tj][kk], wn = Ws[32+tj][kk];
      #pragma unroll
      for (int i=0;i<4;++i){
        float a = As[tb*4+i][kk];
        accR[i] += a*wr; accZ[i] += a*wz; accH[i] += a*wn;
      }
    }
  }
  // phase 1: x-side (weights wi), accumulate n-part into accX
  for (int kt=0; kt<16; ++kt){
    const int kb = kt*32;
    __syncthreads();
    {
      int rl = tid>>5, kl = tid&31;
      #pragma unroll
      for (int rr=0; rr<8; ++rr)
        As[rl+rr*8][kl] = xb[(size_t)(b0+rl+rr*8)*M_ + kb + kl];
      #pragma unroll
      for (int rr=0; rr<6; ++rr){
        int w = rl + rr*8;
        int gi = w>>4, jl = w&15;
        Ws[w][kl] = wi[(size_t)(gi*M_ + j0 + jl)*M_ + kb + kl];
      }
    }
    __syncthreads();
    #pragma unroll
    for (int kk=0; kk<32; ++kk){
      float wr = Ws[tj][kk], wz = Ws[16+tj][kk], wn = Ws[32+tj][kk];
      #pragma unroll
      for (int i=0;i<4;++i){
        float a = As[tb*4+i][kk];
        accR[i] += a*wr; accZ[i] += a*wz; accX[i] += a*wn;
      }
    }
  }

  const int j = j0 + tj;
  const float bir = bi[j], biz = bi[M_+j], bin = bi[2*M_+j];
  const float bhr = bh[j], bhz = bh[M_+j], bhn = bh[2*M_+j];
  #pragma unroll
  for (int i=0;i<4;++i){
    int b = b0 + tb*4 + i;
    float hold = hin[(size_t)b*M_ + j];
    float r = sigmf_(accR[i] + bir + bhr);
    float z = sigmf_(accZ[i] + biz + bhz);
    float n = tanhf(accX[i] + bin + r*(accH[i] + bhn));
    float hn = (1.0f - z)*n + z*hold;
    hout[(size_t)b*M_ + j] = hn;
    seqd[((size_t)b*T_ + te)*M_ + j] = hn;
  }
}

// ---------------- facts = fwd + bwd; factsum[b][m] = sum_t facts
__global__ __launch_bounds__(256) void k_addfacts(float* __restrict__ facts,
    const float* __restrict__ bwds, float* __restrict__ fsum){
  const int b = blockIdx.x;
  const int m = blockIdx.y*256 + threadIdx.x;
  float s = 0.f;
  for (int t=0;t<T_;++t){
    size_t i = ((size_t)(b*T_+t))*M_ + m;
    float f = facts[i] + bwds[i];
    facts[i] = f; s += f;
  }
  fsum[(size_t)b*M_+m] = s;
}

// ---------------- z1+G: fused z-gen GEMM (50176 x 512, K=2048) -> tanh -> dot z2w -> atomicAdd G
__global__ __launch_bounds__(256) void k_z1g(
    const float* __restrict__ facts, const float* __restrict__ q,
    const float* __restrict__ mem, const float* __restrict__ z1w,
    const float* __restrict__ z1b, const float* __restrict__ z2w,
    float* __restrict__ G){
  const int r0 = blockIdx.x*128, m0 = blockIdx.y*64;
  const int tid = threadIdx.x, tx = tid&15, ty = tid>>4;
  __shared__ float As[128][33];
  __shared__ float Ws[64][33];
  __shared__ float red[128][17];
  float acc[8][4] = {};
  for (int kt=0; kt<64; ++kt){
    const int k0 = kt*32;
    const int seg = k0 >> 9;
    const int kin0 = k0 & 511;
    __syncthreads();
    {
      int rl = tid>>5, kl = tid&31;
      #pragma unroll
      for (int rr=0; rr<16; ++rr){
        int r = rl + rr*8;
        int row = r0 + r;
        int b = row / T_;
        float f = facts[(size_t)row*M_ + kin0 + kl];
        float o;
        if (seg==0)      o = f * q[(size_t)b*M_ + kin0 + kl];
        else if (seg==1) o = f * mem[(size_t)b*M_ + kin0 + kl];
        else if (seg==2) o = fabsf(f - q[(size_t)b*M_ + kin0 + kl]);
        else             o = fabsf(f - mem[(size_t)b*M_ + kin0 + kl]);
        As[r][kl] = o;
      }
      #pragma unroll
      for (int rr=0; rr<8; ++rr)
        Ws[rl+rr*8][kl] = z1w[(size_t)(m0+rl+rr*8)*(4*M_) + k0 + kl];
    }
    __syncthreads();
    #pragma unroll
    for (int kk=0;kk<32;++kk){
      float w_[4];
      #pragma unroll
      for (int j=0;j<4;++j) w_[j] = Ws[tx*4+j][kk];
      #pragma unroll
      for (int i=0;i<8;++i){
        float a = As[ty*8+i][kk];
        #pragma unroll
        for (int j=0;j<4;++j) acc[i][j] += a*w_[j];
      }
    }
  }
  float w2[4], b1[4];
  #pragma unroll
  for (int j=0;j<4;++j){ w2[j] = z2w[m0+tx*4+j]; b1[j] = z1b[m0+tx*4+j]; }
  #pragma unroll
  for (int i=0;i<8;++i){
    float s = 0.f;
    #pragma unroll
    for (int j=0;j<4;++j) s += tanhf(acc[i][j] + b1[j]) * w2[j];
    red[ty*8+i][tx] = s;
  }
  __syncthreads();
  if (tid < 128){
    float s = 0.f;
    #pragma unroll
    for (int c=0;c<16;++c) s += red[tid][c];
    atomicAdd(&G[r0+tid], s);
  }
}

// ---------------- softmax over t per b (adds z2b first)
__global__ __launch_bounds__(256) void k_softmax(float* __restrict__ G,
    const float* __restrict__ z2b){
  const int b = blockIdx.x, tid = threadIdx.x;
  __shared__ float s1[4], s2[4];
  bool v = tid < T_;
  float x = v ? (G[(size_t)b*T_+tid] + z2b[0]) : -1e30f;
  float m = x;
  #pragma unroll
  for (int o=32;o;o>>=1) m = fmaxf(m, __shfl_down(m, o, 64));
  if ((tid&63)==0) s1[tid>>6] = m;
  __syncthreads();
  m = fmaxf(fmaxf(s1[0],s1[1]),fmaxf(s1[2],s1[3]));
  float e = v ? expf(x-m) : 0.f;
  float s = e;
  #pragma unroll
  for (int o=32;o;o>>=1) s += __shfl_down(s, o, 64);
  if ((tid&63)==0) s2[tid>>6] = s;
  __syncthreads();
  s = s2[0]+s2[1]+s2[2]+s2[3];
  if (v) G[(size_t)b*T_+tid] = e/s;
}

// ---------------- fr/fw hoist GEMM: out[t][b][j] = facts[b][t][:]·W[j][:] + bias[j]
// z selects (Wr -> fr) or (Wn -> fw). Rows 50176, cols 512, K=512.
__global__ __launch_bounds__(256) void k_frfw(
    const float* __restrict__ facts,
    const float* __restrict__ Wr, const float* __restrict__ Wrb,
    const float* __restrict__ Wn, const float* __restrict__ Wnb,
    float* __restrict__ fr, float* __restrict__ fw){
  const int r0 = blockIdx.x*128, m0 = blockIdx.y*64;
  const float* W = blockIdx.z ? Wn : Wr;
  const float* bias = blockIdx.z ? Wnb : Wrb;
  float* outp = blockIdx.z ? fw : fr;
  const int tid = threadIdx.x, tx = tid&15, ty = tid>>4;
  __shared__ float As[128][33];
  __shared__ float Ws[64][33];
  float acc[8][4] = {};
  for (int kt=0; kt<16; ++kt){
    const int k0 = kt*32;
    __syncthreads();
    {
      int rl = tid>>5, kl = tid&31;
      #pragma unroll
      for (int rr=0; rr<16; ++rr){
        int r = rl + rr*8;
        As[r][kl] = facts[(size_t)(r0+r)*M_ + k0 + kl];
      }
      #pragma unroll
      for (int rr=0; rr<8; ++rr)
        Ws[rl+rr*8][kl] = W[(size_t)(m0+rl+rr*8)*M_ + k0 + kl];
    }
    __syncthreads();
    #pragma unroll
    for (int kk=0;kk<32;++kk){
      float w_[4];
      #pragma unroll
      for (int j=0;j<4;++j) w_[j] = Ws[tx*4+j][kk];
      #pragma unroll
      for (int i=0;i<8;++i){
        float a = As[ty*8+i][kk];
        #pragma unroll
        for (int j=0;j<4;++j) acc[i][j] += a*w_[j];
      }
    }
  }
  float b_[4];
  #pragma unroll
  for (int j=0;j<4;++j) b_[j] = bias[m0+tx*4+j];
  #pragma unroll
  for (int i=0;i<8;++i){
    int row = r0 + ty*8 + i;
    int b = row / T_;
    int t = row - b*T_;
    float* dst = outp + ((size_t)t*B_ + b)*M_ + m0 + tx*4;
    float4 o;
    o.x = acc[i][0]+b_[0]; o.y = acc[i][1]+b_[1];
    o.z = acc[i][2]+b_[2]; o.w = acc[i][3]+b_[3];
    *(float4*)dst = o;
  }
}

// ---------------- AGRU step: only recurrent dot-families (C@Ur, C@U); fr/fw precomputed
__global__ __launch_bounds__(256) void k_agru(
    const float* __restrict__ fr, const float* __restrict__ fw,
    const float* __restrict__ Cin, float* __restrict__ Cout,
    const float* __restrict__ Gp,
    const float* __restrict__ Ur, const float* __restrict__ U,
    const float* __restrict__ Urb, const float* __restrict__ Ub, int t){
  const int b0 = blockIdx.x*16, j0 = blockIdx.y*32;
  const int tid = threadIdx.x, tj = tid&31, tb = tid>>5;
  __shared__ float Cs[16][33], Ws[2][32][33];
  float aUr[2]={0,0}, aU[2]={0,0};
  for (int kt=0; kt<16; ++kt){
    const int kb = kt*32;
    __syncthreads();
    {
      int bl = tid>>5, kl = tid&31;
      #pragma unroll
      for (int rr=0; rr<2; ++rr)
        Cs[bl+rr*8][kl] = Cin[(size_t)(b0+bl+rr*8)*M_ + kb+kl];
      #pragma unroll
      for (int rr=0; rr<4; ++rr){
        int jj = bl + rr*8;
        Ws[0][jj][kl] = Ur[(size_t)(j0+jj)*M_ + kb+kl];
        Ws[1][jj][kl] = U [(size_t)(j0+jj)*M_ + kb+kl];
      }
    }
    __syncthreads();
    #pragma unroll
    for (int kk=0;kk<32;++kk){
      float wur = Ws[0][tj][kk], wu = Ws[1][tj][kk];
      float c0 = Cs[tb*2][kk], c1 = Cs[tb*2+1][kk];
      aUr[0]+=c0*wur; aUr[1]+=c1*wur;
      aU[0]+=c0*wu;   aU[1]+=c1*wu;
    }
  }
  const int j = j0 + tj;
  const float urb = Urb[j], ub = Ub[j];
  const float* frt = fr + (size_t)t*B_*M_;
  const float* fwt = fw + (size_t)t*B_*M_;
  #pragma unroll
  for (int i=0;i<2;++i){
    int b = b0 + tb*2 + i;
    float r  = sigmf_(frt[(size_t)b*M_ + j] + aUr[i] + urb);
    float ht = tanhf(fwt[(size_t)b*M_ + j] + r*(aU[i] + ub));
    float g  = Gp[(size_t)b*T_ + t];
    float cold = Cin[(size_t)b*M_ + j];
    Cout[(size_t)b*M_ + j] = g*ht + (1.0f-g)*cold;
  }
}

// ---------------- memory update: relu([prevM|C|q] @ nmw.T + nmb), K=1536
__global__ __launch_bounds__(256) void k_memupd(
    const float* __restrict__ mp, const float* __restrict__ C,
    const float* __restrict__ q, const float* __restrict__ W,
    const float* __restrict__ bias, float* __restrict__ out){
  const int r0 = blockIdx.x*64, m0 = blockIdx.y*64;
  const int tid = threadIdx.x, tx = tid&15, ty = tid>>4;
  __shared__ float As[64][33], Ws[64][33];
  float acc[4][4] = {};
  for (int kt=0; kt<48; ++kt){
    const int k0 = kt*32;
    const int seg = k0 >> 9;
    const int kin0 = k0 & 511;
    const float* src = (seg==0)? mp : (seg==1)? C : q;
    __syncthreads();
    {
      int rl = tid>>5, kl = tid&31;
      #pragma unroll
      for (int rr=0; rr<8; ++rr){
        As[rl+rr*8][kl] = src[(size_t)(r0+rl+rr*8)*M_ + kin0+kl];
        Ws[rl+rr*8][kl] = W[(size_t)(m0+rl+rr*8)*(3*M_) + k0+kl];
      }
    }
    __syncthreads();
    #pragma unroll
    for (int kk=0;kk<32;++kk){
      float w_[4], a_[4];
      #pragma unroll
      for (int j=0;j<4;++j) w_[j] = Ws[tx*4+j][kk];
      #pragma unroll
      for (int i=0;i<4;++i) a_[i] = As[ty*4+i][kk];
      #pragma unroll
      for (int i=0;i<4;++i)
        #pragma unroll
        for (int j=0;j<4;++j) acc[i][j] += a_[i]*w_[j];
    }
  }
  #pragma unroll
  for (int i=0;i<4;++i)
    #pragma unroll
    for (int j=0;j<4;++j)
      out[(size_t)(r0+ty*4+i)*M_ + m0+tx*4+j] = fmaxf(acc[i][j] + bias[m0+tx*4+j], 0.f);
}

// ---------------- out[b][m] = mem[b][m] * factsum[b][m]
__global__ __launch_bounds__(256) void k_final(const float* __restrict__ mem,
    const float* __restrict__ fs, float* __restrict__ out){
  int i = blockIdx.x*256 + threadIdx.x;
  out[i] = mem[i]*fs[i];
}

extern "C" void kernel_launch(void* const* d_in, const int* in_sizes, int n_in,
                              void* d_out, int out_size, void* d_ws, size_t ws_size,
                              hipStream_t stream){
  const float* vis = (const float*)d_in[0];
  const float* qf  = (const float*)d_in[1];
  const float* cw  = (const float*)d_in[2];
  const float* lw  = (const float*)d_in[3];
  const float* lb  = (const float*)d_in[4];
  const float* wif = (const float*)d_in[5];
  const float* whf = (const float*)d_in[6];
  const float* bif = (const float*)d_in[7];
  const float* bhf = (const float*)d_in[8];
  const float* wib = (const float*)d_in[9];
  const float* whb = (const float*)d_in[10];
  const float* bib = (const float*)d_in[11];
  const float* bhb = (const float*)d_in[12];
  const float* Wr_w = (const float*)d_in[13];
  const float* Wr_b = (const float*)d_in[14];
  const float* Ur_w = (const float*)d_in[15];
  const float* Ur_b = (const float*)d_in[16];
  const float* Wn_w = (const float*)d_in[17]; // em_W_w (input side of n-gate)
  const float* Wn_b = (const float*)d_in[18];
  const float* U_w  = (const float*)d_in[19]; // em_U_w (hidden side of n-gate)
  const float* U_b  = (const float*)d_in[20];
  const float* z1w = (const float*)d_in[21];
  const float* z1b = (const float*)d_in[22];
  const float* z2w = (const float*)d_in[23];
  const float* z2b = (const float*)d_in[24];
  const float* nmw = (const float*)d_in[25];
  const float* nmb = (const float*)d_in[26];
  float* out = (float*)d_out;

  float* p = (float*)d_ws;
  float* vseq  = p; p += (size_t)T_*B_*M_;   // reused as fw during episodic phase
  float* facts = p; p += (size_t)B_*T_*M_;
  float* bwds  = p; p += (size_t)B_*T_*M_;   // reused as fr during episodic phase
  float* fsum  = p; p += B_*M_;
  float* q     = p; p += B_*M_;
  float* hf0 = p; p += B_*M_;
  float* hf1 = p; p += B_*M_;
  float* hb0 = p; p += B_*M_;
  float* hb1 = p; p += B_*M_;
  float* mem0 = p; p += B_*M_;
  float* mem1 = p; p += B_*M_;
  float* C0 = p; p += B_*M_;
  float* C1 = p; p += B_*M_;
  float* G  = p; p += B_*T_;

  // conv + q projection
  k_conv<<<dim3(BT_/128, M_/64), 256, 0, stream>>>(vis, cw, vseq);
  k_linq<<<dim3(B_/64, M_/64), 256, 0, stream>>>(qf, lw, lb, q);

  // bidirectional GRU scan (input projection fused into each step)
  hipMemsetAsync(hf0, 0, (size_t)B_*M_*4, stream);
  hipMemsetAsync(hb0, 0, (size_t)B_*M_*4, stream);
  for (int s=0; s<T_; ++s){
    float* hfi = (s&1)? hf1:hf0; float* hfo = (s&1)? hf0:hf1;
    float* hbi = (s&1)? hb1:hb0; float* hbo = (s&1)? hb0:hb1;
    k_gru<<<dim3(B_/64, M_/16, 2), 256, 0, stream>>>(vseq, hfi,hfo, hbi,hbo,
        wif,whf,bif,bhf, wib,whb,bib,bhb, facts, bwds, s);
  }
  k_addfacts<<<dim3(B_, M_/256), 256, 0, stream>>>(facts, bwds, fsum);

  // vseq and bwds are dead now -> reuse as fw / fr
  float* fr = bwds;
  float* fw = vseq;

  // episodic memory: 3 layers
  const float* mprev = q;
  for (int l=0; l<NL; ++l){
    hipMemsetAsync(G, 0, (size_t)B_*T_*4, stream);
    k_z1g<<<dim3(BT_/128, M_/64), 256, 0, stream>>>(facts, q, mprev,
        z1w + (size_t)l*M_*4*M_, z1b + (size_t)l*M_, z2w + (size_t)l*M_, G);
    k_softmax<<<dim3(B_), 256, 0, stream>>>(G, z2b + l);
    // hoisted fact projections for this layer (independent of scan state)
    k_frfw<<<dim3(BT_/128, M_/64, 2), 256, 0, stream>>>(facts,
        Wr_w + (size_t)l*M_*M_, Wr_b + (size_t)l*M_,
        Wn_w + (size_t)l*M_*M_, Wn_b + (size_t)l*M_, fr, fw);
    hipMemsetAsync(C0, 0, (size_t)B_*M_*4, stream);
    for (int t=0; t<T_; ++t){
      float* ci = (t&1)? C1:C0; float* co = (t&1)? C0:C1;
      k_agru<<<dim3(B_/16, M_/32), 256, 0, stream>>>(fr, fw, ci, co, G,
          Ur_w + (size_t)l*M_*M_, U_w + (size_t)l*M_*M_,
          Ur_b + (size_t)l*M_, U_b + (size_t)l*M_, t);
    }
    // T_ even -> final C lands in C0
    float* mout = (l&1)? mem1 : mem0;
    k_memupd<<<dim3(B_/64, M_/64), 256, 0, stream>>>(mprev, C0, q,
        nmw + (size_t)l*M_*3*M_, nmb + (size_t)l*M_, mout);
    mprev = mout;
  }
  k_final<<<dim3((B_*M_)/256), 256, 0, stream>>>(mprev, fsum, out);
}

// Round 3
// 37501.535 us; speedup vs baseline: 1.6350x; 1.6350x over previous
//
#include <hip/hip_runtime.h>
#include <cmath>

#define B_ 256
#define V_ 2048
#define T_ 196
#define Q_ 1024
#define M_ 512
#define NL 3
#define BT_ (B_*T_)
#define TM3 (3*M_)

__device__ __forceinline__ float sigmf_(float x){ return 1.0f/(1.0f+expf(-x)); }

// ================= conv: vseq[t][b][m] = relu(sum_v vis[b][v][t]*cw[m][v])
// 128 rows ((b,t)) x 128 cols (m), K=V_. Col-major LDS, b128 fragment reads.
__global__ __launch_bounds__(256) void k_conv(const float* __restrict__ vis,
        const float* __restrict__ cw, float* __restrict__ vseq){
  const int r0 = blockIdx.x*128, m0 = blockIdx.y*128;
  const int tid = threadIdx.x, tx = tid&15, ty = tid>>4;
  __shared__ __align__(16) float As[32][132];
  __shared__ __align__(16) float Ws[32][132];
  float acc[8][8] = {};
  const int rl = tid&127, kh = tid>>7;          // A-stage: row rl, k = kh+2*rr
  const int row_l = r0 + rl;
  const int bl = row_l / T_;
  const int tl = row_l - bl*T_;
  const int klw = tid&31, cc = tid>>5;          // W-stage: k klw, col cc+8*rr
  for (int kt=0; kt<64; ++kt){
    const int v0 = kt*32;
    __syncthreads();
    #pragma unroll
    for (int rr=0; rr<16; ++rr){
      int kl = kh + rr*2;
      As[kl][rl] = vis[((size_t)bl*V_ + v0 + kl)*T_ + tl];
    }
    #pragma unroll
    for (int rr=0; rr<16; ++rr)
      Ws[klw][cc + rr*8] = cw[(size_t)(m0+cc+rr*8)*V_ + v0 + klw];
    __syncthreads();
    #pragma unroll
    for (int kk=0; kk<32; ++kk){
      float4 a0 = *(const float4*)&As[kk][ty*8];
      float4 a1 = *(const float4*)&As[kk][ty*8+4];
      float4 b0 = *(const float4*)&Ws[kk][tx*8];
      float4 b1 = *(const float4*)&Ws[kk][tx*8+4];
      float av[8] = {a0.x,a0.y,a0.z,a0.w,a1.x,a1.y,a1.z,a1.w};
      float bv[8] = {b0.x,b0.y,b0.z,b0.w,b1.x,b1.y,b1.z,b1.w};
      #pragma unroll
      for (int i=0;i<8;++i)
        #pragma unroll
        for (int j=0;j<8;++j) acc[i][j] += av[i]*bv[j];
    }
  }
  #pragma unroll
  for (int i=0;i<8;++i){
    int row = r0 + ty*8 + i;
    int b = row / T_;
    int t = row - b*T_;
    float* dst = vseq + ((size_t)t*B_ + b)*M_ + m0 + tx*8;
    float4 o0, o1;
    o0.x=fmaxf(acc[i][0],0.f); o0.y=fmaxf(acc[i][1],0.f);
    o0.z=fmaxf(acc[i][2],0.f); o0.w=fmaxf(acc[i][3],0.f);
    o1.x=fmaxf(acc[i][4],0.f); o1.y=fmaxf(acc[i][5],0.f);
    o1.z=fmaxf(acc[i][6],0.f); o1.w=fmaxf(acc[i][7],0.f);
    *(float4*)dst = o0; *(float4*)(dst+4) = o1;
  }
}

// ================= linq: q[b][m] = relu(qf[b]·lw[m] + lb[m]), K=Q_ (small; 64x64)
__global__ __launch_bounds__(256) void k_linq(const float* __restrict__ A,
    const float* __restrict__ W, const float* __restrict__ bias,
    float* __restrict__ out){
  const int r0 = blockIdx.x*64, m0 = blockIdx.y*64;
  const int tid = threadIdx.x, tx = tid&15, ty = tid>>4;
  __shared__ float As[64][33], Ws[64][33];
  float acc[4][4] = {};
  for (int kt=0; kt<32; ++kt){
    const int k0 = kt*32;
    __syncthreads();
    {
      int rl = tid>>5, kl = tid&31;
      #pragma unroll
      for (int rr=0; rr<8; ++rr){
        As[rl+rr*8][kl] = A[(size_t)(r0+rl+rr*8)*Q_ + k0+kl];
        Ws[rl+rr*8][kl] = W[(size_t)(m0+rl+rr*8)*Q_ + k0+kl];
      }
    }
    __syncthreads();
    #pragma unroll
    for (int kk=0;kk<32;++kk){
      float w_[4], a_[4];
      #pragma unroll
      for (int j=0;j<4;++j) w_[j] = Ws[tx*4+j][kk];
      #pragma unroll
      for (int i=0;i<4;++i) a_[i] = As[ty*4+i][kk];
      #pragma unroll
      for (int i=0;i<4;++i)
        #pragma unroll
        for (int j=0;j<4;++j) acc[i][j] += a_[i]*w_[j];
    }
  }
  #pragma unroll
  for (int i=0;i<4;++i)
    #pragma unroll
    for (int j=0;j<4;++j)
      out[(size_t)(r0+ty*4+i)*M_ + m0+tx*4+j] = fmaxf(acc[i][j] + bias[m0+tx*4+j], 0.f);
}

// ================= xp hoist: xp[dir][t*B+b][3M] = vseq·wi^T + bi  (128x128, K=512)
__global__ __launch_bounds__(256) void k_xp(const float* __restrict__ vseq,
    const float* __restrict__ wif, const float* __restrict__ bif,
    const float* __restrict__ wib, const float* __restrict__ bib,
    float* __restrict__ xp){
  const int r0 = blockIdx.x*128, m0 = blockIdx.y*128;
  const int dir = blockIdx.z;
  const float* W = dir? wib : wif;
  const float* bias = dir? bib : bif;
  const int tid = threadIdx.x, tx = tid&15, ty = tid>>4;
  __shared__ __align__(16) float As[32][132];
  __shared__ __align__(16) float Ws[32][132];
  float acc[8][8] = {};
  const int klA = tid&31, rwA = tid>>5;
  for (int kt=0; kt<16; ++kt){
    const int k0 = kt*32;
    __syncthreads();
    #pragma unroll
    for (int rr=0; rr<16; ++rr){
      As[klA][rwA+rr*8] = vseq[(size_t)(r0+rwA+rr*8)*M_ + k0+klA];
      Ws[klA][rwA+rr*8] = W[(size_t)(m0+rwA+rr*8)*M_ + k0+klA];
    }
    __syncthreads();
    #pragma unroll
    for (int kk=0;kk<32;++kk){
      float4 a0 = *(const float4*)&As[kk][ty*8];
      float4 a1 = *(const float4*)&As[kk][ty*8+4];
      float4 b0 = *(const float4*)&Ws[kk][tx*8];
      float4 b1 = *(const float4*)&Ws[kk][tx*8+4];
      float av[8] = {a0.x,a0.y,a0.z,a0.w,a1.x,a1.y,a1.z,a1.w};
      float bv[8] = {b0.x,b0.y,b0.z,b0.w,b1.x,b1.y,b1.z,b1.w};
      #pragma unroll
      for (int i=0;i<8;++i)
        #pragma unroll
        for (int j=0;j<8;++j) acc[i][j] += av[i]*bv[j];
    }
  }
  float b_[8];
  #pragma unroll
  for (int j=0;j<8;++j) b_[j] = bias[m0+tx*8+j];
  #pragma unroll
  for (int i=0;i<8;++i){
    float* dst = xp + ((size_t)dir*BT_ + r0+ty*8+i)*TM3 + m0 + tx*8;
    float4 o0, o1;
    o0.x=acc[i][0]+b_[0]; o0.y=acc[i][1]+b_[1]; o0.z=acc[i][2]+b_[2]; o0.w=acc[i][3]+b_[3];
    o1.x=acc[i][4]+b_[4]; o1.y=acc[i][5]+b_[5]; o1.z=acc[i][6]+b_[6]; o1.w=acc[i][7]+b_[7];
    *(float4*)dst = o0; *(float4*)(dst+4) = o1;
  }
}

// ================= GRU step, hoisted path: h-side only (K=512), xp precomputed.
// tile 32b x 32j per dir, 512 threads, register-prefetch pipelined staging.
__global__ __launch_bounds__(512) void k_gruh(
    const float* __restrict__ xp,
    const float* __restrict__ hf_in, float* __restrict__ hf_out,
    const float* __restrict__ hb_in, float* __restrict__ hb_out,
    const float* __restrict__ whf, const float* __restrict__ bhf,
    const float* __restrict__ whb, const float* __restrict__ bhb,
    float* __restrict__ facts, float* __restrict__ bwds, int s){
  const int dir = blockIdx.z;
  const int b0 = blockIdx.x*32, j0 = blockIdx.y*32;
  const int tid = threadIdx.x, tj = tid&31, tb = tid>>5;   // tb 0..15
  const int te = dir ? (T_-1-s) : s;
  const float* hin = dir? hb_in : hf_in;
  float* hout = dir? hb_out : hf_out;
  const float* wh = dir? whb : whf;
  const float* bh = dir? bhb : bhf;
  const float* xpt = xp + ((size_t)dir*BT_ + (size_t)te*B_)*TM3;
  float* seqd = dir? bwds : facts;
  __shared__ __align__(16) float As[32][36];    // [k][32 b]
  __shared__ __align__(16) float Ws[32][100];   // [k][96 = 3 gates x 32 j]
  float accR[2]={0,0}, accZ[2]={0,0}, accH[2]={0,0};
  const int kl = tid&31, xs = tid>>5;           // staging coords
  float pa[2], pw[6];
  // preload kt=0
  {
    const int kb = 0;
    #pragma unroll
    for (int rr=0; rr<2; ++rr)
      pa[rr] = hin[(size_t)(b0+xs+16*rr)*M_ + kb+kl];
    #pragma unroll
    for (int rr=0; rr<6; ++rr){
      int wl = xs + 16*rr, gi = wl>>5, jl = wl&31;
      pw[rr] = wh[(size_t)(gi*M_ + j0+jl)*M_ + kb+kl];
    }
  }
  for (int kt=0; kt<16; ++kt){
    #pragma unroll
    for (int rr=0; rr<2; ++rr) As[kl][xs+16*rr] = pa[rr];
    #pragma unroll
    for (int rr=0; rr<6; ++rr) Ws[kl][xs+16*rr] = pw[rr];
    __syncthreads();
    if (kt < 15){
      const int kb = (kt+1)*32;
      #pragma unroll
      for (int rr=0; rr<2; ++rr)
        pa[rr] = hin[(size_t)(b0+xs+16*rr)*M_ + kb+kl];
      #pragma unroll
      for (int rr=0; rr<6; ++rr){
        int wl = xs + 16*rr, gi = wl>>5, jl = wl&31;
        pw[rr] = wh[(size_t)(gi*M_ + j0+jl)*M_ + kb+kl];
      }
    }
    #pragma unroll
    for (int kk=0; kk<32; ++kk){
      float2 a = *(const float2*)&As[kk][tb*2];
      float wr = Ws[kk][tj], wz = Ws[kk][32+tj], wn = Ws[kk][64+tj];
      accR[0]+=a.x*wr; accR[1]+=a.y*wr;
      accZ[0]+=a.x*wz; accZ[1]+=a.y*wz;
      accH[0]+=a.x*wn; accH[1]+=a.y*wn;
    }
    __syncthreads();
  }
  const int j = j0 + tj;
  const float bhr = bh[j], bhz = bh[M_+j], bhn = bh[2*M_+j];
  #pragma unroll
  for (int i=0;i<2;++i){
    int b = b0 + tb*2 + i;
    const float* xb = xpt + (size_t)b*TM3;
    float xr = xb[j], xz = xb[M_+j], xn = xb[2*M_+j];
    float hold = hin[(size_t)b*M_ + j];
    float r = sigmf_(xr + accR[i] + bhr);
    float z = sigmf_(xz + accZ[i] + bhz);
    float n = tanhf(xn + r*(accH[i] + bhn));
    float hn = (1.0f - z)*n + z*hold;
    hout[(size_t)b*M_ + j] = hn;
    seqd[((size_t)b*T_ + te)*M_ + j] = hn;
  }
}

// Wait: As read uses [tb*2] but epilogue uses b0+tb*2+i -> consistent.

// ================= GRU step, fallback (ws too small): full K=1024 fused (round-2 kernel)
__global__ __launch_bounds__(256) void k_gru(
    const float* __restrict__ vseq,
    const float* __restrict__ hf_in, float* __restrict__ hf_out,
    const float* __restrict__ hb_in, float* __restrict__ hb_out,
    const float* __restrict__ wif, const float* __restrict__ whf,
    const float* __restrict__ bif, const float* __restrict__ bhf,
    const float* __restrict__ wib, const float* __restrict__ whb,
    const float* __restrict__ bib, const float* __restrict__ bhb,
    float* __restrict__ facts, float* __restrict__ bwds, int s){
  const int dir = blockIdx.z;
  const int b0 = blockIdx.x*64, j0 = blockIdx.y*16;
  const int tid = threadIdx.x, tb = tid&15, tj = tid>>4;
  const int te = dir ? (T_-1-s) : s;
  const float* hin = dir? hb_in : hf_in;
  float* hout = dir? hb_out : hf_out;
  const float* wi = dir? wib : wif;
  const float* wh = dir? whb : whf;
  const float* bi = dir? bib : bif;
  const float* bh = dir? bhb : bhf;
  const float* xb = vseq + (size_t)te*B_*M_;
  float* seqd = dir? bwds : facts;
  __shared__ float As[64][33];
  __shared__ float Ws[48][33];
  float accR[4]={0,0,0,0}, accZ[4]={0,0,0,0}, accH[4]={0,0,0,0}, accX[4]={0,0,0,0};
  for (int kt=0; kt<16; ++kt){
    const int kb = kt*32;
    __syncthreads();
    {
      int rl = tid>>5, kl = tid&31;
      #pragma unroll
      for (int rr=0; rr<8; ++rr)
        As[rl+rr*8][kl] = hin[(size_t)(b0+rl+rr*8)*M_ + kb + kl];
      #pragma unroll
      for (int rr=0; rr<6; ++rr){
        int w = rl + rr*8;
        int gi = w>>4, jl = w&15;
        Ws[w][kl] = wh[(size_t)(gi*M_ + j0 + jl)*M_ + kb + kl];
      }
    }
    __syncthreads();
    #pragma unroll
    for (int kk=0; kk<32; ++kk){
      float wr = Ws[tj][kk], wz = Ws[16+tj][kk], wn = Ws[32+tj][kk];
      #pragma unroll
      for (int i=0;i<4;++i){
        float a = As[tb*4+i][kk];
        accR[i] += a*wr; accZ[i] += a*wz; accH[i] += a*wn;
      }
    }
  }
  for (int kt=0; kt<16; ++kt){
    const int kb = kt*32;
    __syncthreads();
    {
      int rl = tid>>5, kl = tid&31;
      #pragma unroll
      for (int rr=0; rr<8; ++rr)
        As[rl+rr*8][kl] = xb[(size_t)(b0+rl+rr*8)*M_ + kb + kl];
      #pragma unroll
      for (int rr=0; rr<6; ++rr){
        int w = rl + rr*8;
        int gi = w>>4, jl = w&15;
        Ws[w][kl] = wi[(size_t)(gi*M_ + j0 + jl)*M_ + kb + kl];
      }
    }
    __syncthreads();
    #pragma unroll
    for (int kk=0; kk<32; ++kk){
      float wr = Ws[tj][kk], wz = Ws[16+tj][kk], wn = Ws[32+tj][kk];
      #pragma unroll
      for (int i=0;i<4;++i){
        float a = As[tb*4+i][kk];
        accR[i] += a*wr; accZ[i] += a*wz; accX[i] += a*wn;
      }
    }
  }
  const int j = j0 + tj;
  const float bir = bi[j], biz = bi[M_+j], bin = bi[2*M_+j];
  const float bhr = bh[j], bhz = bh[M_+j], bhn = bh[2*M_+j];
  #pragma unroll
  for (int i=0;i<4;++i){
    int b = b0 + tb*4 + i;
    float hold = hin[(size_t)b*M_ + j];
    float r = sigmf_(accR[i] + bir + bhr);
    float z = sigmf_(accZ[i] + biz + bhz);
    float n = tanhf(accX[i] + bin + r*(accH[i] + bhn));
    float hn = (1.0f - z)*n + z*hold;
    hout[(size_t)b*M_ + j] = hn;
    seqd[((size_t)b*T_ + te)*M_ + j] = hn;
  }
}

// ================= facts = fwd + bwd; factsum[b][m]
__global__ __launch_bounds__(256) void k_addfacts(float* __restrict__ facts,
    const float* __restrict__ bwds, float* __restrict__ fsum){
  const int b = blockIdx.x;
  const int m = blockIdx.y*256 + threadIdx.x;
  float s = 0.f;
  for (int t=0;t<T_;++t){
    size_t i = ((size_t)(b*T_+t))*M_ + m;
    float f = facts[i] + bwds[i];
    facts[i] = f; s += f;
  }
  fsum[(size_t)b*M_+m] = s;
}

// ================= z1+G: fused z-gen (128x128, K=2048) -> tanh -> dot z2w -> atomicAdd
__global__ __launch_bounds__(256) void k_z1g(
    const float* __restrict__ facts, const float* __restrict__ q,
    const float* __restrict__ mem, const float* __restrict__ z1w,
    const float* __restrict__ z1b, const float* __restrict__ z2w,
    float* __restrict__ G){
  const int r0 = blockIdx.x*128, m0 = blockIdx.y*128;
  const int tid = threadIdx.x, tx = tid&15, ty = tid>>4;
  __shared__ __align__(16) float As[32][132];
  __shared__ __align__(16) float Ws[32][132];
  __shared__ float red[128][17];
  float acc[8][8] = {};
  const int klA = tid&31, rwA = tid>>5;
  for (int kt=0; kt<64; ++kt){
    const int k0 = kt*32;
    const int seg = k0 >> 9;
    const int kin0 = k0 & 511;
    __syncthreads();
    #pragma unroll
    for (int rr=0; rr<16; ++rr){
      int row = r0 + rwA + rr*8;
      int b = row / T_;
      float f = facts[(size_t)row*M_ + kin0 + klA];
      float o;
      if (seg==0)      o = f * q[(size_t)b*M_ + kin0 + klA];
      else if (seg==1) o = f * mem[(size_t)b*M_ + kin0 + klA];
      else if (seg==2) o = fabsf(f - q[(size_t)b*M_ + kin0 + klA]);
      else             o = fabsf(f - mem[(size_t)b*M_ + kin0 + klA]);
      As[klA][rwA+rr*8] = o;
    }
    #pragma unroll
    for (int rr=0; rr<16; ++rr)
      Ws[klA][rwA+rr*8] = z1w[(size_t)(m0+rwA+rr*8)*(4*M_) + k0 + klA];
    __syncthreads();
    #pragma unroll
    for (int kk=0;kk<32;++kk){
      float4 a0 = *(const float4*)&As[kk][ty*8];
      float4 a1 = *(const float4*)&As[kk][ty*8+4];
      float4 b0 = *(const float4*)&Ws[kk][tx*8];
      float4 b1 = *(const float4*)&Ws[kk][tx*8+4];
      float av[8] = {a0.x,a0.y,a0.z,a0.w,a1.x,a1.y,a1.z,a1.w};
      float bv[8] = {b0.x,b0.y,b0.z,b0.w,b1.x,b1.y,b1.z,b1.w};
      #pragma unroll
      for (int i=0;i<8;++i)
        #pragma unroll
        for (int j=0;j<8;++j) acc[i][j] += av[i]*bv[j];
    }
  }
  float w2[8], b1[8];
  #pragma unroll
  for (int j=0;j<8;++j){ w2[j] = z2w[m0+tx*8+j]; b1[j] = z1b[m0+tx*8+j]; }
  #pragma unroll
  for (int i=0;i<8;++i){
    float s = 0.f;
    #pragma unroll
    for (int j=0;j<8;++j) s += tanhf(acc[i][j] + b1[j]) * w2[j];
    red[ty*8+i][tx] = s;
  }
  __syncthreads();
  if (tid < 128){
    float s = 0.f;
    #pragma unroll
    for (int c=0;c<16;++c) s += red[tid][c];
    atomicAdd(&G[r0+tid], s);
  }
}

// ================= softmax over t per b
__global__ __launch_bounds__(256) void k_softmax(float* __restrict__ G,
    const float* __restrict__ z2b){
  const int b = blockIdx.x, tid = threadIdx.x;
  __shared__ float s1[4], s2[4];
  bool v = tid < T_;
  float x = v ? (G[(size_t)b*T_+tid] + z2b[0]) : -1e30f;
  float m = x;
  #pragma unroll
  for (int o=32;o;o>>=1) m = fmaxf(m, __shfl_down(m, o, 64));
  if ((tid&63)==0) s1[tid>>6] = m;
  __syncthreads();
  m = fmaxf(fmaxf(s1[0],s1[1]),fmaxf(s1[2],s1[3]));
  float e = v ? expf(x-m) : 0.f;
  float s = e;
  #pragma unroll
  for (int o=32;o;o>>=1) s += __shfl_down(s, o, 64);
  if ((tid&63)==0) s2[tid>>6] = s;
  __syncthreads();
  s = s2[0]+s2[1]+s2[2]+s2[3];
  if (v) G[(size_t)b*T_+tid] = e/s;
}

// ================= fr/fw hoist (128x128, K=512), out scatter to [t][b][m]
__global__ __launch_bounds__(256) void k_frfw(
    const float* __restrict__ facts,
    const float* __restrict__ Wr, const float* __restrict__ Wrb,
    const float* __restrict__ Wn, const float* __restrict__ Wnb,
    float* __restrict__ fr, float* __restrict__ fw){
  const int r0 = blockIdx.x*128, m0 = blockIdx.y*128;
  const float* W = blockIdx.z ? Wn : Wr;
  const float* bias = blockIdx.z ? Wnb : Wrb;
  float* outp = blockIdx.z ? fw : fr;
  const int tid = threadIdx.x, tx = tid&15, ty = tid>>4;
  __shared__ __align__(16) float As[32][132];
  __shared__ __align__(16) float Ws[32][132];
  float acc[8][8] = {};
  const int klA = tid&31, rwA = tid>>5;
  for (int kt=0; kt<16; ++kt){
    const int k0 = kt*32;
    __syncthreads();
    #pragma unroll
    for (int rr=0; rr<16; ++rr){
      As[klA][rwA+rr*8] = facts[(size_t)(r0+rwA+rr*8)*M_ + k0 + klA];
      Ws[klA][rwA+rr*8] = W[(size_t)(m0+rwA+rr*8)*M_ + k0 + klA];
    }
    __syncthreads();
    #pragma unroll
    for (int kk=0;kk<32;++kk){
      float4 a0 = *(const float4*)&As[kk][ty*8];
      float4 a1 = *(const float4*)&As[kk][ty*8+4];
      float4 b0 = *(const float4*)&Ws[kk][tx*8];
      float4 b1 = *(const float4*)&Ws[kk][tx*8+4];
      float av[8] = {a0.x,a0.y,a0.z,a0.w,a1.x,a1.y,a1.z,a1.w};
      float bv[8] = {b0.x,b0.y,b0.z,b0.w,b1.x,b1.y,b1.z,b1.w};
      #pragma unroll
      for (int i=0;i<8;++i)
        #pragma unroll
        for (int j=0;j<8;++j) acc[i][j] += av[i]*bv[j];
    }
  }
  float b_[8];
  #pragma unroll
  for (int j=0;j<8;++j) b_[j] = bias[m0+tx*8+j];
  #pragma unroll
  for (int i=0;i<8;++i){
    int row = r0 + ty*8 + i;
    int b = row / T_;
    int t = row - b*T_;
    float* dst = outp + ((size_t)t*B_ + b)*M_ + m0 + tx*8;
    float4 o0, o1;
    o0.x=acc[i][0]+b_[0]; o0.y=acc[i][1]+b_[1]; o0.z=acc[i][2]+b_[2]; o0.w=acc[i][3]+b_[3];
    o1.x=acc[i][4]+b_[4]; o1.y=acc[i][5]+b_[5]; o1.z=acc[i][6]+b_[6]; o1.w=acc[i][7]+b_[7];
    *(float4*)dst = o0; *(float4*)(dst+4) = o1;
  }
}

// ================= AGRU step: recurrent dots only; tile 8b x 32j, pipelined staging
__global__ __launch_bounds__(256) void k_agru(
    const float* __restrict__ fr, const float* __restrict__ fw,
    const float* __restrict__ Cin, float* __restrict__ Cout,
    const float* __restrict__ Gp,
    const float* __restrict__ Ur, const float* __restrict__ U,
    const float* __restrict__ Urb, const float* __restrict__ Ub, int t){
  const int b0 = blockIdx.x*8, j0 = blockIdx.y*32;
  const int tid = threadIdx.x, tj = tid&31, tb = tid>>5;  // tb 0..7
  __shared__ __align__(16) float Cs[32][12];
  __shared__ __align__(16) float Ws[2][32][36];
  float aUr = 0.f, aU = 0.f;
  const int kl = tid&31, xs = tid>>5;
  float pc, pw[8];
  {
    const int kb = 0;
    pc = Cin[(size_t)(b0+xs)*M_ + kb+kl];
    #pragma unroll
    for (int rr=0; rr<4; ++rr){
      int jl = xs + 8*rr;
      pw[rr]   = Ur[(size_t)(j0+jl)*M_ + kb+kl];
      pw[4+rr] = U [(size_t)(j0+jl)*M_ + kb+kl];
    }
  }
  for (int kt=0; kt<16; ++kt){
    Cs[kl][xs] = pc;
    #pragma unroll
    for (int rr=0; rr<4; ++rr){
      int jl = xs + 8*rr;
      Ws[0][kl][jl] = pw[rr];
      Ws[1][kl][jl] = pw[4+rr];
    }
    __syncthreads();
    if (kt < 15){
      const int kb = (kt+1)*32;
      pc = Cin[(size_t)(b0+xs)*M_ + kb+kl];
      #pragma unroll
      for (int rr=0; rr<4; ++rr){
        int jl = xs + 8*rr;
        pw[rr]   = Ur[(size_t)(j0+jl)*M_ + kb+kl];
        pw[4+rr] = U [(size_t)(j0+jl)*M_ + kb+kl];
      }
    }
    #pragma unroll
    for (int kk=0; kk<32; ++kk){
      float c = Cs[kk][tb];
      aUr += c*Ws[0][kk][tj];
      aU  += c*Ws[1][kk][tj];
    }
    __syncthreads();
  }
  const int j = j0 + tj;
  const int b = b0 + tb;
  float r  = sigmf_(fr[((size_t)t*B_+b)*M_ + j] + aUr + Urb[j]);
  float ht = tanhf(fw[((size_t)t*B_+b)*M_ + j] + r*(aU + Ub[j]));
  float g  = Gp[(size_t)b*T_ + t];
  float cold = Cin[(size_t)b*M_ + j];
  Cout[(size_t)b*M_ + j] = g*ht + (1.0f-g)*cold;
}

// ================= memory update: relu([prevM|C|q] @ nmw.T + nmb), K=1536 (64x64)
__global__ __launch_bounds__(256) void k_memupd(
    const float* __restrict__ mp, const float* __restrict__ C,
    const float* __restrict__ q, const float* __restrict__ W,
    const float* __restrict__ bias, float* __restrict__ out){
  const int r0 = blockIdx.x*64, m0 = blockIdx.y*64;
  const int tid = threadIdx.x, tx = tid&15, ty = tid>>4;
  __shared__ float As[64][33], Ws[64][33];
  float acc[4][4] = {};
  for (int kt=0; kt<48; ++kt){
    const int k0 = kt*32;
    const int seg = k0 >> 9;
    const int kin0 = k0 & 511;
    const float* src = (seg==0)? mp : (seg==1)? C : q;
    __syncthreads();
    {
      int rl = tid>>5, kl = tid&31;
      #pragma unroll
      for (int rr=0; rr<8; ++rr){
        As[rl+rr*8][kl] = src[(size_t)(r0+rl+rr*8)*M_ + kin0+kl];
        Ws[rl+rr*8][kl] = W[(size_t)(m0+rl+rr*8)*(3*M_) + k0+kl];
      }
    }
    __syncthreads();
    #pragma unroll
    for (int kk=0;kk<32;++kk){
      float w_[4], a_[4];
      #pragma unroll
      for (int j=0;j<4;++j) w_[j] = Ws[tx*4+j][kk];
      #pragma unroll
      for (int i=0;i<4;++i) a_[i] = As[ty*4+i][kk];
      #pragma unroll
      for (int i=0;i<4;++i)
        #pragma unroll
        for (int j=0;j<4;++j) acc[i][j] += a_[i]*w_[j];
    }
  }
  #pragma unroll
  for (int i=0;i<4;++i)
    #pragma unroll
    for (int j=0;j<4;++j)
      out[(size_t)(r0+ty*4+i)*M_ + m0+tx*4+j] = fmaxf(acc[i][j] + bias[m0+tx*4+j], 0.f);
}

// ================= out = mem * factsum
__global__ __launch_bounds__(256) void k_final(const float* __restrict__ mem,
    const float* __restrict__ fs, float* __restrict__ out){
  int i = blockIdx.x*256 + threadIdx.x;
  out[i] = mem[i]*fs[i];
}

extern "C" void kernel_launch(void* const* d_in, const int* in_sizes, int n_in,
                              void* d_out, int out_size, void* d_ws, size_t ws_size,
                              hipStream_t stream){
  const float* vis = (const float*)d_in[0];
  const float* qf  = (const float*)d_in[1];
  const float* cw  = (const float*)d_in[2];
  const float* lw  = (const float*)d_in[3];
  const float* lb  = (const float*)d_in[4];
  const float* wif = (const float*)d_in[5];
  const float* whf = (const float*)d_in[6];
  const float* bif = (const float*)d_in[7];
  const float* bhf = (const float*)d_in[8];
  const float* wib = (const float*)d_in[9];
  const float* whb = (const float*)d_in[10];
  const float* bib = (const float*)d_in[11];
  const float* bhb = (const float*)d_in[12];
  const float* Wr_w = (const float*)d_in[13];
  const float* Wr_b = (const float*)d_in[14];
  const float* Ur_w = (const float*)d_in[15];
  const float* Ur_b = (const float*)d_in[16];
  const float* Wn_w = (const float*)d_in[17];
  const float* Wn_b = (const float*)d_in[18];
  const float* U_w  = (const float*)d_in[19];
  const float* U_b  = (const float*)d_in[20];
  const float* z1w = (const float*)d_in[21];
  const float* z1b = (const float*)d_in[22];
  const float* z2w = (const float*)d_in[23];
  const float* z2b = (const float*)d_in[24];
  const float* nmw = (const float*)d_in[25];
  const float* nmb = (const float*)d_in[26];
  float* out = (float*)d_out;

  float* p = (float*)d_ws;
  float* vseq  = p; p += (size_t)T_*B_*M_;   // reused as fw in episodic phase
  float* facts = p; p += (size_t)B_*T_*M_;
  float* bwds  = p; p += (size_t)B_*T_*M_;   // reused as fr in episodic phase
  float* fsum  = p; p += B_*M_;
  float* q     = p; p += B_*M_;
  float* hf0 = p; p += B_*M_;
  float* hf1 = p; p += B_*M_;
  float* hb0 = p; p += B_*M_;
  float* hb1 = p; p += B_*M_;
  float* mem0 = p; p += B_*M_;
  float* mem1 = p; p += B_*M_;
  float* C0 = p; p += B_*M_;
  float* C1 = p; p += B_*M_;
  float* G  = p; p += B_*T_;
  float* xp = p; // optional: 2*BT_*TM3 floats
  size_t base_bytes = (size_t)((char*)p - (char*)d_ws);
  size_t xp_bytes = (size_t)2*BT_*TM3*sizeof(float);
  const bool hoist = ws_size >= base_bytes + xp_bytes;

  k_conv<<<dim3(BT_/128, M_/128), 256, 0, stream>>>(vis, cw, vseq);
  k_linq<<<dim3(B_/64, M_/64), 256, 0, stream>>>(qf, lw, lb, q);

  hipMemsetAsync(hf0, 0, (size_t)B_*M_*4, stream);
  hipMemsetAsync(hb0, 0, (size_t)B_*M_*4, stream);
  if (hoist){
    k_xp<<<dim3(BT_/128, TM3/128, 2), 256, 0, stream>>>(vseq, wif, bif, wib, bib, xp);
    for (int s=0; s<T_; ++s){
      float* hfi = (s&1)? hf1:hf0; float* hfo = (s&1)? hf0:hf1;
      float* hbi = (s&1)? hb1:hb0; float* hbo = (s&1)? hb0:hb1;
      k_gruh<<<dim3(B_/32, M_/32, 2), 512, 0, stream>>>(xp, hfi,hfo, hbi,hbo,
          whf,bhf, whb,bhb, facts, bwds, s);
    }
  } else {
    for (int s=0; s<T_; ++s){
      float* hfi = (s&1)? hf1:hf0; float* hfo = (s&1)? hf0:hf1;
      float* hbi = (s&1)? hb1:hb0; float* hbo = (s&1)? hb0:hb1;
      k_gru<<<dim3(B_/64, M_/16, 2), 256, 0, stream>>>(vseq, hfi,hfo, hbi,hbo,
          wif,whf,bif,bhf, wib,whb,bib,bhb, facts, bwds, s);
    }
  }
  k_addfacts<<<dim3(B_, M_/256), 256, 0, stream>>>(facts, bwds, fsum);

  float* fr = bwds;
  float* fw = vseq;

  const float* mprev = q;
  for (int l=0; l<NL; ++l){
    hipMemsetAsync(G, 0, (size_t)B_*T_*4, stream);
    k_z1g<<<dim3(BT_/128, M_/128), 256, 0, stream>>>(facts, q, mprev,
        z1w + (size_t)l*M_*4*M_, z1b + (size_t)l*M_, z2w + (size_t)l*M_, G);
    k_softmax<<<dim3(B_), 256, 0, stream>>>(G, z2b + l);
    k_frfw<<<dim3(BT_/128, M_/128, 2), 256, 0, stream>>>(facts,
        Wr_w + (size_t)l*M_*M_, Wr_b + (size_t)l*M_,
        Wn_w + (size_t)l*M_*M_, Wn_b + (size_t)l*M_, fr, fw);
    hipMemsetAsync(C0, 0, (size_t)B_*M_*4, stream);
    for (int t=0; t<T_; ++t){
      float* ci = (t&1)? C1:C0; float* co = (t&1)? C0:C1;
      k_agru<<<dim3(B_/8, M_/32), 256, 0, stream>>>(fr, fw, ci, co, G,
          Ur_w + (size_t)l*M_*M_, U_w + (size_t)l*M_*M_,
          Ur_b + (size_t)l*M_, U_b + (size_t)l*M_, t);
    }
    float* mout = (l&1)? mem1 : mem0;
    k_memupd<<<dim3(B_/64, M_/64), 256, 0, stream>>>(mprev, C0, q,
        nmw + (size_t)l*M_*3*M_, nmb + (size_t)l*M_, mout);
    mprev = mout;
  }
  k_final<<<dim3((B_*M_)/256), 256, 0, stream>>>(mprev, fsum, out);
}